// Round 1
// baseline (1457.579 us; speedup 1.0000x reference)
//
#include <hip/hip_runtime.h>
#include <stdint.h>

#define B 4
#define T 256
#define V 1024
#define S 64
#define DIM 1024
#define CV 256

// ---- workspace layout (4-byte element offsets) ----
enum : int {
    WKP_OFF  = 0,                       // [CV*DIM] Wu@Wk
    WVP_OFF  = WKP_OFF + CV*DIM,        // [CV*DIM] Wu@Wv
    BK_OFF   = WVP_OFF + CV*DIM,        // [DIM]    bu@Wk
    BV_OFF   = BK_OFF + DIM,            // [DIM]    bu@Wv
    Z_OFF    = BV_OFF + DIM,            // [B*T*CV] Wk'@x per token
    C0_OFF   = Z_OFF + B*T*CV,          // [B*T]    bk.x
    W_OFF    = C0_OFF + B*T,            // [B*T*CV] sum_s p*vision
    RS_OFF   = W_OFF + B*T*CV,          // [B*T]    sum_s p
    PVAL_OFF = RS_OFF + B*T,            // [B*T*S]  p values (compacted)
    PIDX_OFF = PVAL_OFF + B*T*S,        // [B*T*S]  v indices (compacted, int)
    CNT_OFF  = PIDX_OFF + B*T*S,        // [B*T]    atomic counters   (zeroed)
    DENOM_OFF= CNT_OFF + B*T,           // [B]      per-batch sum exp (zeroed)
    FLAGA_OFF= DENOM_OFF + B,           // [1] saw nonzero byte at off%4!=0 (zeroed)
    FLAGB_OFF= FLAGA_OFF + 1,           // [1] saw byte 0x3f                (zeroed)
    WS_TOTAL = FLAGB_OFF + 1
};

// ---- sniff mask encoding: int32 (0), uint8 (1), float32 (2) ----
__global__ void detect_mask_mode(const uint8_t* __restrict__ m, int nbytes,
                                 int* flagA, int* flagB) {
    int i = blockIdx.x * blockDim.x + threadIdx.x;
    int stride = gridDim.x * blockDim.x;
    int a = 0, bfl = 0;
    for (; i < nbytes; i += stride) {
        uint8_t v = m[i];
        if (v) {
            if (i & 3) a = 1;
            if (v == 0x3f) bfl = 1;
        }
    }
    if (a) *flagA = 1;
    if (bfl) *flagB = 1;
}

// ---- Wk' = Wu@Wk, Wv' = Wu@Wv ----
// 256 blocks: which(2) x cvBlk(32, 8 rows each) x dBlk(4, 256 cols each)
__global__ void prep_wp(const float* __restrict__ Wu, const float* __restrict__ Wk,
                        const float* __restrict__ Wv, float* __restrict__ ws) {
    __shared__ float su[8 * 1024];
    int blk = blockIdx.x;
    int which = blk >> 7;
    int rem = blk & 127;
    int cv0 = (rem >> 2) * 8;
    int d = (rem & 3) * 256 + threadIdx.x;
    const float* Wsel = which ? Wv : Wk;
    float* out = ws + (which ? WVP_OFF : WKP_OFF);
    for (int l = threadIdx.x; l < 8 * 1024; l += 256)
        su[l] = Wu[(cv0 + (l >> 10)) * DIM + (l & 1023)];
    __syncthreads();
    float acc[8] = {0,0,0,0,0,0,0,0};
    for (int e = 0; e < DIM; e++) {
        float wv = Wsel[e * DIM + d];
#pragma unroll
        for (int j = 0; j < 8; j++) acc[j] += su[j * 1024 + e] * wv;
    }
#pragma unroll
    for (int j = 0; j < 8; j++) out[(cv0 + j) * DIM + d] = acc[j];
}

// ---- bk = bu@Wk, bv = bu@Wv ----
__global__ void prep_bias(const float* __restrict__ bu, const float* __restrict__ Wk,
                          const float* __restrict__ Wv, float* __restrict__ ws) {
    int which = blockIdx.x >> 2;
    int d = (blockIdx.x & 3) * 256 + threadIdx.x;
    const float* Wsel = which ? Wv : Wk;
    float acc = 0.f;
    for (int e = 0; e < DIM; e++) acc += bu[e] * Wsel[e * DIM + d];
    ws[(which ? BV_OFF : BK_OFF) + d] = acc;
}

// ---- z[bt,:] = Wk' @ x[bt,:],  c0[bt] = bk . x[bt,:] ----
__global__ void k2_z(const float* __restrict__ x, float* __restrict__ ws) {
    __shared__ float xs[DIM];
    __shared__ float red[256];
    int bt = blockIdx.x;
    for (int l = threadIdx.x; l < DIM; l += 256) xs[l] = x[(size_t)bt * DIM + l];
    __syncthreads();
    int cv = threadIdx.x;
    const float4* row = (const float4*)(ws + WKP_OFF + (size_t)cv * DIM);
    float acc = 0.f;
    for (int i = 0; i < DIM / 4; i++) {
        float4 f = row[i];
        acc += f.x * xs[4*i] + f.y * xs[4*i+1] + f.z * xs[4*i+2] + f.w * xs[4*i+3];
    }
    ws[Z_OFF + bt * CV + cv] = acc;
    float part = 0.f;
    for (int l = threadIdx.x; l < DIM; l += 256) part += ws[BK_OFF + l] * xs[l];
    red[threadIdx.x] = part;
    __syncthreads();
    for (int s2 = 128; s2 > 0; s2 >>= 1) {
        if (threadIdx.x < s2) red[threadIdx.x] += red[threadIdx.x + s2];
        __syncthreads();
    }
    if (threadIdx.x == 0) ws[C0_OFF + bt] = red[0];
}

// ---- masked logits -> p = exp(logit), compacted (idx,p), denom[b] += sum p ----
__global__ void k3_p(const float* __restrict__ vision, const void* __restrict__ maskp,
                     float* __restrict__ ws, int* __restrict__ wsi) {
    __shared__ float zs[CV];
    __shared__ float red[256];
    __shared__ float c0s;
    __shared__ int mode_s;
    int bt = blockIdx.x;
    int b = bt >> 8;
    int t = bt & 255;
    if (threadIdx.x < CV) zs[threadIdx.x] = ws[Z_OFF + bt * CV + threadIdx.x];
    if (threadIdx.x == 0) {
        c0s = ws[C0_OFF + bt];
        int fA = wsi[FLAGA_OFF], fB = wsi[FLAGB_OFF];
        mode_s = fA ? (fB ? 2 : 1) : 0;
    }
    __syncthreads();
    int mode = mode_s;
    float c0v = c0s;
    float psum = 0.f;
    for (int rep = 0; rep < V / 256; rep++) {
        int v = rep * 256 + threadIdx.x;
        size_t mi = ((size_t)b * V + v) * T + t;
        bool sel;
        if (mode == 0)      sel = ((const int*)maskp)[mi] != 0;
        else if (mode == 1) sel = ((const uint8_t*)maskp)[mi] != 0;
        else                sel = ((const float*)maskp)[mi] != 0.f;
        if (sel) {
            const float4* vr = (const float4*)(vision + ((size_t)b * V + v) * CV);
            float acc = 0.f;
            for (int i = 0; i < CV / 4; i++) {
                float4 f = vr[i];
                acc += f.x * zs[4*i] + f.y * zs[4*i+1] + f.z * zs[4*i+2] + f.w * zs[4*i+3];
            }
            float p = expf((acc + c0v) * 0.03125f);  // 1/sqrt(DIM) = 1/32
            int pos = atomicAdd(&wsi[CNT_OFF + bt], 1);
            if (pos < S) {
                wsi[PIDX_OFF + bt * S + pos] = v;
                ws[PVAL_OFF + bt * S + pos] = p;
            }
            psum += p;
        }
    }
    red[threadIdx.x] = psum;
    __syncthreads();
    for (int s2 = 128; s2 > 0; s2 >>= 1) {
        if (threadIdx.x < s2) red[threadIdx.x] += red[threadIdx.x + s2];
        __syncthreads();
    }
    if (threadIdx.x == 0) atomicAdd(&ws[DENOM_OFF + b], red[0]);
}

// ---- w[bt,:] = sum_s p_s * vision[b, idx_s, :],  rowsum[bt] = sum_s p_s ----
__global__ void k4_w(const float* __restrict__ vision, float* __restrict__ ws,
                     const int* __restrict__ wsi) {
    __shared__ float lp[S];
    __shared__ int li[S];
    int bt = blockIdx.x;
    int b = bt >> 8;
    if (threadIdx.x < S) {
        lp[threadIdx.x] = ws[PVAL_OFF + bt * S + threadIdx.x];
        li[threadIdx.x] = wsi[PIDX_OFF + bt * S + threadIdx.x];
    }
    __syncthreads();
    int cv = threadIdx.x;
    float acc = 0.f;
    for (int s = 0; s < S; s++)
        acc += lp[s] * vision[((size_t)b * V + li[s]) * CV + cv];
    ws[W_OFF + bt * CV + cv] = acc;
    if (threadIdx.x == 0) {
        float rs = 0.f;
        for (int s = 0; s < S; s++) rs += lp[s];
        ws[RS_OFF + bt] = rs;
    }
}

// ---- out[bt,:] = x[bt,:] + (w[bt,:] @ Wv' + rowsum*bv) / denom[b] ----
__global__ void k5_out(const float* __restrict__ x, const float* __restrict__ ws,
                       float* __restrict__ out) {
    __shared__ float sw[CV];
    __shared__ float srs, sinv;
    int bt = blockIdx.x;
    int b = bt >> 8;
    if (threadIdx.x < CV) sw[threadIdx.x] = ws[W_OFF + bt * CV + threadIdx.x];
    if (threadIdx.x == 0) {
        srs = ws[RS_OFF + bt];
        sinv = 1.0f / ws[DENOM_OFF + b];
    }
    __syncthreads();
    float acc[4] = {0.f, 0.f, 0.f, 0.f};
    for (int cv = 0; cv < CV; cv++) {
        float wc = sw[cv];
        const float* wr = ws + WVP_OFF + (size_t)cv * DIM;
#pragma unroll
        for (int r = 0; r < 4; r++) acc[r] += wc * wr[r * 256 + threadIdx.x];
    }
    float rs = srs, inv = sinv;
#pragma unroll
    for (int r = 0; r < 4; r++) {
        int d = r * 256 + threadIdx.x;
        out[(size_t)bt * DIM + d] =
            x[(size_t)bt * DIM + d] + (acc[r] + rs * ws[BV_OFF + d]) * inv;
    }
}

extern "C" void kernel_launch(void* const* d_in, const int* in_sizes, int n_in,
                              void* d_out, int out_size, void* d_ws, size_t ws_size,
                              hipStream_t stream) {
    (void)in_sizes; (void)n_in; (void)out_size; (void)ws_size;
    const float* x      = (const float*)d_in[0];
    const float* vision = (const float*)d_in[1];
    const void*  mask   = d_in[2];
    const float* Wu     = (const float*)d_in[3];
    const float* bu     = (const float*)d_in[4];
    const float* Wk     = (const float*)d_in[5];
    const float* Wv     = (const float*)d_in[6];
    float* out = (float*)d_out;
    float* ws  = (float*)d_ws;
    int*   wsi = (int*)d_ws;

    // zero cnt/denom/flags (ws is re-poisoned to 0xAA before every launch)
    hipMemsetAsync((char*)d_ws + (size_t)CNT_OFF * 4, 0,
                   (size_t)(WS_TOTAL - CNT_OFF) * 4, stream);

    detect_mask_mode<<<64, 256, 0, stream>>>((const uint8_t*)mask, B * V * T,
                                             wsi + FLAGA_OFF, wsi + FLAGB_OFF);
    prep_wp<<<256, 256, 0, stream>>>(Wu, Wk, Wv, ws);
    prep_bias<<<8, 256, 0, stream>>>(bu, Wk, Wv, ws);
    k2_z<<<B * T, 256, 0, stream>>>(x, ws);
    k3_p<<<B * T, 256, 0, stream>>>(vision, mask, ws, wsi);
    k4_w<<<B * T, 256, 0, stream>>>(vision, ws, wsi);
    k5_out<<<B * T, 256, 0, stream>>>(x, ws, out);
}

// Round 2
// 617.458 us; speedup vs baseline: 2.3606x; 2.3606x over previous
//
#include <hip/hip_runtime.h>
#include <stdint.h>

#define B 4
#define T 256
#define V 1024
#define S 64
#define DIM 1024
#define CV 256

// ---- workspace layout (4-byte element offsets) ----
enum : int {
    WKPT_OFF = 0,                        // [DIM*CV]  (Wu@Wk)^T  (d-major)
    WVP_OFF  = WKPT_OFF + DIM*CV,        // [CV*DIM]  Wu@Wv      (cv-major)
    BK_OFF   = WVP_OFF + CV*DIM,         // [DIM]     bu@Wk
    BV_OFF   = BK_OFF + DIM,             // [DIM]     bu@Wv
    Z_OFF    = BV_OFF + DIM,             // [B*T*CV]  z per token
    C0_OFF   = Z_OFF + B*T*CV,           // [B*T]     bk.x per token
    W_OFF    = C0_OFF + B*T,             // [B*T*CV]  sum_s p*vision
    RS_OFF   = W_OFF + B*T*CV,           // [B*T]     sum_s p
    PIDX_OFF = RS_OFF + B*T,             // [B*T*S]   selected v indices (int)
    DENOM_OFF= PIDX_OFF + B*T*S,         // [B]       per-batch sum exp (zeroed)
    FLAGA_OFF= DENOM_OFF + B,            // [1] nonzero byte at off%4!=0 (zeroed)
    FLAGB_OFF= FLAGA_OFF + 1,            // [1] saw byte 0x3f            (zeroed)
    WS_TOTAL = FLAGB_OFF + 1
};

// ---- sniff mask encoding: int32/f32 (4-byte) vs uint8 ----
__global__ void detect_mask_mode(const uint8_t* __restrict__ m, int nbytes,
                                 int* __restrict__ flagA, int* __restrict__ flagB) {
    int i = blockIdx.x * blockDim.x + threadIdx.x;
    int stride = gridDim.x * blockDim.x;
    int a = 0, bfl = 0;
    for (; i < nbytes; i += stride) {
        uint8_t v = m[i];
        if (v) {
            if (i & 3) a = 1;
            if (v == 0x3f) bfl = 1;
        }
    }
    if (a) *flagA = 1;
    if (bfl) *flagB = 1;
}

// ---- per-(b,t) index compaction; coalesced mask reads, no atomics ----
__global__ void compact_idx(const void* __restrict__ maskp, int* __restrict__ wsi) {
    int b = blockIdx.x, t = threadIdx.x;
    int fA = wsi[FLAGA_OFF], fB = wsi[FLAGB_OFF];
    bool byteMode = (fA && !fB);           // f32 1.0f has nonzero int bits, int-read ok
    int base = PIDX_OFF + (b * T + t) * S;
    int cnt = 0;
    if (byteMode) {
        const uint8_t* m = (const uint8_t*)maskp + (size_t)b * V * T + t;
        for (int v = 0; v < V; v++)
            if (m[(size_t)v * T] != 0) { if (cnt < S) wsi[base + cnt] = v; cnt++; }
    } else {
        const int* m = (const int*)maskp + (size_t)b * V * T + t;
        for (int v = 0; v < V; v++)
            if (m[(size_t)v * T] != 0) { if (cnt < S) wsi[base + cnt] = v; cnt++; }
    }
    for (int j = (cnt < S ? cnt : S); j < S; j++) wsi[base + j] = 0;  // poison-safety
}

// ---- Wkp^T (which=0) and Wvp (which=1): C[m=cv][n=d] = sum_e Wu[m,e]*Wsel[e,n] ----
__global__ void g_prep(const float* __restrict__ Wu, const float* __restrict__ Wk,
                       const float* __restrict__ Wv, float* __restrict__ ws) {
    __shared__ float As[64][9];
    int bx = blockIdx.x;
    int which = bx >> 7;
    int rem = bx & 127;
    int m0 = (rem >> 2) * 8;
    int n = (rem & 3) * 256 + threadIdx.x;
    const float* Bm = which ? Wv : Wk;
    float acc[8] = {0, 0, 0, 0, 0, 0, 0, 0};
    for (int kc = 0; kc < DIM; kc += 64) {
        for (int l = threadIdx.x; l < 512; l += 256) {
            int ki = l & 63, mi = l >> 6;
            As[ki][mi] = Wu[(size_t)(m0 + mi) * DIM + kc + ki];
        }
        __syncthreads();
#pragma unroll 8
        for (int ki = 0; ki < 64; ki++) {
            float bv = Bm[(size_t)(kc + ki) * DIM + n];
#pragma unroll
            for (int mi = 0; mi < 8; mi++) acc[mi] += As[ki][mi] * bv;
        }
        __syncthreads();
    }
    if (which) {
#pragma unroll
        for (int mi = 0; mi < 8; mi++)
            ws[WVP_OFF + (size_t)(m0 + mi) * DIM + n] = acc[mi];
    } else {  // store transposed: WkpT[d=n][cv=m0..m0+7]
        float4* dst = (float4*)(ws + WKPT_OFF + (size_t)n * CV + m0);
        dst[0] = make_float4(acc[0], acc[1], acc[2], acc[3]);
        dst[1] = make_float4(acc[4], acc[5], acc[6], acc[7]);
    }
}

// ---- bk = bu@Wk, bv = bu@Wv ----
__global__ void prep_bias(const float* __restrict__ bu, const float* __restrict__ Wk,
                          const float* __restrict__ Wv, float* __restrict__ ws) {
    int which = blockIdx.x >> 2;
    int d = (blockIdx.x & 3) * 256 + threadIdx.x;
    const float* Wsel = which ? Wv : Wk;
    float acc = 0.f;
    for (int e = 0; e < DIM; e++) acc += bu[e] * Wsel[(size_t)e * DIM + d];
    ws[(which ? BV_OFF : BK_OFF) + d] = acc;
}

// ---- Z[bt,cv] = sum_d x[bt,d]*WkpT[d,cv]; fused c0[bt] = sum_d x[bt,d]*bk[d] ----
__global__ void g_z(const float* __restrict__ x, float* __restrict__ ws) {
    __shared__ float As[64][9];
    int m0 = blockIdx.x * 8;
    int n = threadIdx.x;
    float acc[8] = {0, 0, 0, 0, 0, 0, 0, 0};
    float c0p[8] = {0, 0, 0, 0, 0, 0, 0, 0};
    for (int kc = 0; kc < DIM; kc += 64) {
        for (int l = threadIdx.x; l < 512; l += 256) {
            int ki = l & 63, mi = l >> 6;
            As[ki][mi] = x[(size_t)(m0 + mi) * DIM + kc + ki];
        }
        __syncthreads();
        if (threadIdx.x < 64) {
            float bk = ws[BK_OFF + kc + threadIdx.x];
#pragma unroll
            for (int mi = 0; mi < 8; mi++) c0p[mi] += As[threadIdx.x][mi] * bk;
        }
#pragma unroll 8
        for (int ki = 0; ki < 64; ki++) {
            float bv = ws[WKPT_OFF + (size_t)(kc + ki) * CV + n];
#pragma unroll
            for (int mi = 0; mi < 8; mi++) acc[mi] += As[ki][mi] * bv;
        }
        __syncthreads();
    }
#pragma unroll
    for (int mi = 0; mi < 8; mi++)
        ws[Z_OFF + (size_t)(m0 + mi) * CV + n] = acc[mi];
    if (threadIdx.x < 64) {
#pragma unroll
        for (int mi = 0; mi < 8; mi++) {
            float vsum = c0p[mi];
            for (int off = 32; off > 0; off >>= 1) vsum += __shfl_xor(vsum, off);
            if (threadIdx.x == 0) ws[C0_OFF + m0 + mi] = vsum;
        }
    }
}

// ---- per (b,t): p_s = exp((vision_row_s . z + c0)/32); w = sum p_s*row_s ----
__global__ void g_k3(const float* __restrict__ vision, float* __restrict__ ws,
                     int* __restrict__ wsi) {
    __shared__ float zs[CV];
    __shared__ float ps[S];
    __shared__ int idxs[S];
    __shared__ float c0s;
    int bt = blockIdx.x, b = bt >> 8;
    int tid = threadIdx.x;
    zs[tid] = ws[Z_OFF + (size_t)bt * CV + tid];
    if (tid < S) idxs[tid] = wsi[PIDX_OFF + bt * S + tid];
    if (tid == 0) c0s = ws[C0_OFF + bt];
    __syncthreads();
    int wave = tid >> 6, lane = tid & 63;
    float4 zv = ((const float4*)zs)[lane];
    float c0v = c0s;
    const float4* vis4 = (const float4*)(vision + (size_t)b * V * CV);
    for (int j = 0; j < 16; j++) {
        int s = wave * 16 + j;
        int row = idxs[s];
        float4 f = vis4[(size_t)row * (CV / 4) + lane];
        float part = f.x * zv.x + f.y * zv.y + f.z * zv.z + f.w * zv.w;
        for (int off = 32; off > 0; off >>= 1) part += __shfl_xor(part, off);
        if (lane == 0) ps[s] = expf((part + c0v) * 0.03125f);
    }
    __syncthreads();
    if (tid < 64) {
        float rs = ps[tid];
        for (int off = 32; off > 0; off >>= 1) rs += __shfl_xor(rs, off);
        if (tid == 0) {
            ws[RS_OFF + bt] = rs;
            atomicAdd(ws + DENOM_OFF + b, rs);
        }
    }
    // w accumulation: thread = cv, coalesced row reads (L2-hot from phase 1)
    float acc = 0.f;
#pragma unroll 4
    for (int s = 0; s < S; s++)
        acc += ps[s] * vision[((size_t)b * V + idxs[s]) * CV + tid];
    ws[W_OFF + (size_t)bt * CV + tid] = acc;
}

// ---- out[bt,d] = x[bt,d] + (sum_cv W[bt,cv]*Wvp[cv,d] + rs[bt]*bv[d]) / denom[b] ----
__global__ void g_out(const float* __restrict__ x, const float* __restrict__ ws,
                      float* __restrict__ out) {
    __shared__ float As[64][9];
    int mt = blockIdx.x & 127, nt = blockIdx.x >> 7;
    int m0 = mt * 8;
    int n = nt * 256 + threadIdx.x;
    float acc[8] = {0, 0, 0, 0, 0, 0, 0, 0};
    for (int kc = 0; kc < CV; kc += 64) {
        for (int l = threadIdx.x; l < 512; l += 256) {
            int ki = l & 63, mi = l >> 6;
            As[ki][mi] = ws[W_OFF + (size_t)(m0 + mi) * CV + kc + ki];
        }
        __syncthreads();
#pragma unroll 8
        for (int ki = 0; ki < 64; ki++) {
            float bv = ws[WVP_OFF + (size_t)(kc + ki) * DIM + n];
#pragma unroll
            for (int mi = 0; mi < 8; mi++) acc[mi] += As[ki][mi] * bv;
        }
        __syncthreads();
    }
    float bvv = ws[BV_OFF + n];
#pragma unroll
    for (int mi = 0; mi < 8; mi++) {
        int bt = m0 + mi;
        float rs = ws[RS_OFF + bt];
        float inv = 1.0f / ws[DENOM_OFF + (bt >> 8)];
        out[(size_t)bt * DIM + n] = x[(size_t)bt * DIM + n] + (acc[mi] + rs * bvv) * inv;
    }
}

extern "C" void kernel_launch(void* const* d_in, const int* in_sizes, int n_in,
                              void* d_out, int out_size, void* d_ws, size_t ws_size,
                              hipStream_t stream) {
    (void)in_sizes; (void)n_in; (void)out_size; (void)ws_size;
    const float* x      = (const float*)d_in[0];
    const float* vision = (const float*)d_in[1];
    const void*  mask   = d_in[2];
    const float* Wu     = (const float*)d_in[3];
    const float* bu     = (const float*)d_in[4];
    const float* Wk     = (const float*)d_in[5];
    const float* Wv     = (const float*)d_in[6];
    float* out = (float*)d_out;
    float* ws  = (float*)d_ws;
    int*   wsi = (int*)d_ws;

    hipMemsetAsync((char*)d_ws + (size_t)DENOM_OFF * 4, 0,
                   (size_t)(WS_TOTAL - DENOM_OFF) * 4, stream);

    detect_mask_mode<<<64, 256, 0, stream>>>((const uint8_t*)mask, B * V * T,
                                             wsi + FLAGA_OFF, wsi + FLAGB_OFF);
    compact_idx<<<B, 256, 0, stream>>>(mask, wsi);
    g_prep<<<256, 256, 0, stream>>>(Wu, Wk, Wv, ws);
    prep_bias<<<8, 256, 0, stream>>>(bu, Wk, Wv, ws);
    g_z<<<128, 256, 0, stream>>>(x, ws);
    g_k3<<<B * T, 256, 0, stream>>>(vision, ws, wsi);
    g_out<<<512, 256, 0, stream>>>(x, ws, out);
}

// Round 3
// 309.688 us; speedup vs baseline: 4.7066x; 1.9938x over previous
//
#include <hip/hip_runtime.h>
#include <stdint.h>

#define B 4
#define T 256
#define V 1024
#define S 64
#define DIM 1024
#define CV 256

// ---- workspace layout (4-byte element offsets) ----
enum : int {
    WKPT_OFF = 0,                        // [DIM*CV]  (Wu@Wk)^T  (d-major)
    WVP_OFF  = WKPT_OFF + DIM*CV,        // [CV*DIM]  Wu@Wv      (cv-major)
    BK_OFF   = WVP_OFF + CV*DIM,         // [DIM]     bu@Wk
    BV_OFF   = BK_OFF + DIM,             // [DIM]     bu@Wv
    Z_OFF    = BV_OFF + DIM,             // [B*T*CV]  z per token
    C0_OFF   = Z_OFF + B*T*CV,           // [B*T]     bk.x per token
    W_OFF    = C0_OFF + B*T,             // [B*T*CV]  sum_s p*vision
    RS_OFF   = W_OFF + B*T*CV,           // [B*T]     sum_s p
    PIDX_OFF = RS_OFF + B*T,             // [B*T*S]   selected v indices (int)
    CNT_OFF  = PIDX_OFF + B*T*S,         // [B*T*16]  per-chunk mask counts
    DENOM_OFF= CNT_OFF + B*T*16,         // [B]       per-batch sum exp (zeroed)
    FLAGA_OFF= DENOM_OFF + B,            // [1] nonzero byte at off%4!=0 (zeroed)
    FLAGB_OFF= FLAGA_OFF + 1,            // [1] saw byte 0x3f            (zeroed)
    WS_TOTAL = FLAGB_OFF + 1
};

// ---- sniff mask encoding: int32/f32 (4-byte) vs uint8 ----
__global__ void detect_mask_mode(const uint8_t* __restrict__ m, int nbytes,
                                 int* __restrict__ flagA, int* __restrict__ flagB) {
    int i = blockIdx.x * blockDim.x + threadIdx.x;
    int stride = gridDim.x * blockDim.x;
    int a = 0, bfl = 0;
    for (; i < nbytes; i += stride) {
        uint8_t v = m[i];
        if (v) {
            if (i & 3) a = 1;
            if (v == 0x3f) bfl = 1;
        }
    }
    if (a) *flagA = 1;
    if (bfl) *flagB = 1;
}

// ---- phase 1: count set mask bits per (b,t,chunk-of-64-v); coalesced in t ----
__global__ void count_chunks(const void* __restrict__ maskp, int* __restrict__ wsi) {
    int blk = blockIdx.x;            // b*16 + chunk
    int b = blk >> 4, c = blk & 15;
    int t = threadIdx.x;
    bool byteMode = (wsi[FLAGA_OFF] && !wsi[FLAGB_OFF]);
    int v0 = c * 64;
    int cnt = 0;
    if (byteMode) {
        const uint8_t* m = (const uint8_t*)maskp + (size_t)(b * V + v0) * T + t;
#pragma unroll 8
        for (int j = 0; j < 64; j++) cnt += (m[(size_t)j * T] != 0);
    } else {
        const int* m = (const int*)maskp + (size_t)(b * V + v0) * T + t;
#pragma unroll 8
        for (int j = 0; j < 64; j++) cnt += (m[(size_t)j * T] != 0);
    }
    wsi[CNT_OFF + (b * T + t) * 16 + c] = cnt;
}

// ---- phase 2: rescan chunk, scatter indices at prefix offset ----
__global__ void write_idx(const void* __restrict__ maskp, int* __restrict__ wsi) {
    int blk = blockIdx.x;            // b*16 + chunk
    int b = blk >> 4, c = blk & 15;
    int t = threadIdx.x;
    bool byteMode = (wsi[FLAGA_OFF] && !wsi[FLAGB_OFF]);
    int bt = b * T + t;
    int off = 0, total = 0;
#pragma unroll
    for (int cc = 0; cc < 16; cc++) {
        int cn = wsi[CNT_OFF + bt * 16 + cc];
        if (cc < c) off += cn;
        total += cn;
    }
    int base = PIDX_OFF + bt * S;
    int v0 = c * 64;
    if (byteMode) {
        const uint8_t* m = (const uint8_t*)maskp + (size_t)(b * V + v0) * T + t;
        for (int j = 0; j < 64; j++)
            if (m[(size_t)j * T] != 0) { if (off < S) wsi[base + off] = v0 + j; off++; }
    } else {
        const int* m = (const int*)maskp + (size_t)(b * V + v0) * T + t;
        for (int j = 0; j < 64; j++)
            if (m[(size_t)j * T] != 0) { if (off < S) wsi[base + off] = v0 + j; off++; }
    }
    if (c == 15)  // last chunk knows the grand total: zero-fill unused slots
        for (int j = (total < S ? total : S); j < S; j++) wsi[base + j] = 0;
}

// ---- Wkp^T (which=0) and Wvp (which=1): C[m=cv][n=d] = sum_e Wu[m,e]*Wsel[e,n] ----
__global__ void g_prep(const float* __restrict__ Wu, const float* __restrict__ Wk,
                       const float* __restrict__ Wv, float* __restrict__ ws) {
    __shared__ float As[64][9];
    int bx = blockIdx.x;
    int which = bx >> 7;
    int rem = bx & 127;
    int m0 = (rem >> 2) * 8;
    int n = (rem & 3) * 256 + threadIdx.x;
    const float* Bm = which ? Wv : Wk;
    float acc[8] = {0, 0, 0, 0, 0, 0, 0, 0};
    for (int kc = 0; kc < DIM; kc += 64) {
        for (int l = threadIdx.x; l < 512; l += 256) {
            int ki = l & 63, mi = l >> 6;
            As[ki][mi] = Wu[(size_t)(m0 + mi) * DIM + kc + ki];
        }
        __syncthreads();
#pragma unroll 8
        for (int ki = 0; ki < 64; ki++) {
            float bv = Bm[(size_t)(kc + ki) * DIM + n];
#pragma unroll
            for (int mi = 0; mi < 8; mi++) acc[mi] += As[ki][mi] * bv;
        }
        __syncthreads();
    }
    if (which) {
#pragma unroll
        for (int mi = 0; mi < 8; mi++)
            ws[WVP_OFF + (size_t)(m0 + mi) * DIM + n] = acc[mi];
    } else {  // store transposed: WkpT[d=n][cv=m0..m0+7]
        float4* dst = (float4*)(ws + WKPT_OFF + (size_t)n * CV + m0);
        dst[0] = make_float4(acc[0], acc[1], acc[2], acc[3]);
        dst[1] = make_float4(acc[4], acc[5], acc[6], acc[7]);
    }
}

// ---- bk = bu@Wk, bv = bu@Wv ----
__global__ void prep_bias(const float* __restrict__ bu, const float* __restrict__ Wk,
                          const float* __restrict__ Wv, float* __restrict__ ws) {
    int which = blockIdx.x >> 2;
    int d = (blockIdx.x & 3) * 256 + threadIdx.x;
    const float* Wsel = which ? Wv : Wk;
    float acc = 0.f;
    for (int e = 0; e < DIM; e++) acc += bu[e] * Wsel[(size_t)e * DIM + d];
    ws[(which ? BV_OFF : BK_OFF) + d] = acc;
}

// ---- Z[bt,cv] = sum_d x[bt,d]*WkpT[d,cv]; fused c0[bt] = sum_d x[bt,d]*bk[d] ----
__global__ void g_z(const float* __restrict__ x, float* __restrict__ ws) {
    __shared__ float As[64][9];
    int m0 = blockIdx.x * 8;
    int n = threadIdx.x;
    float acc[8] = {0, 0, 0, 0, 0, 0, 0, 0};
    float c0p[8] = {0, 0, 0, 0, 0, 0, 0, 0};
    for (int kc = 0; kc < DIM; kc += 64) {
        for (int l = threadIdx.x; l < 512; l += 256) {
            int ki = l & 63, mi = l >> 6;
            As[ki][mi] = x[(size_t)(m0 + mi) * DIM + kc + ki];
        }
        __syncthreads();
        if (threadIdx.x < 64) {
            float bk = ws[BK_OFF + kc + threadIdx.x];
#pragma unroll
            for (int mi = 0; mi < 8; mi++) c0p[mi] += As[threadIdx.x][mi] * bk;
        }
#pragma unroll 8
        for (int ki = 0; ki < 64; ki++) {
            float bv = ws[WKPT_OFF + (size_t)(kc + ki) * CV + n];
#pragma unroll
            for (int mi = 0; mi < 8; mi++) acc[mi] += As[ki][mi] * bv;
        }
        __syncthreads();
    }
#pragma unroll
    for (int mi = 0; mi < 8; mi++)
        ws[Z_OFF + (size_t)(m0 + mi) * CV + n] = acc[mi];
    if (threadIdx.x < 64) {
#pragma unroll
        for (int mi = 0; mi < 8; mi++) {
            float vsum = c0p[mi];
            for (int off = 32; off > 0; off >>= 1) vsum += __shfl_xor(vsum, off);
            if (threadIdx.x == 0) ws[C0_OFF + m0 + mi] = vsum;
        }
    }
}

// ---- per (b,t): p_s = exp((vision_row_s . z + c0)/32); w = sum p_s*row_s ----
__global__ void g_k3(const float* __restrict__ vision, float* __restrict__ ws,
                     int* __restrict__ wsi) {
    __shared__ float zs[CV];
    __shared__ float ps[S];
    __shared__ int idxs[S];
    __shared__ float c0s;
    int bt = blockIdx.x, b = bt >> 8;
    int tid = threadIdx.x;
    zs[tid] = ws[Z_OFF + (size_t)bt * CV + tid];
    if (tid < S) idxs[tid] = wsi[PIDX_OFF + bt * S + tid];
    if (tid == 0) c0s = ws[C0_OFF + bt];
    __syncthreads();
    int wave = tid >> 6, lane = tid & 63;
    float4 zv = ((const float4*)zs)[lane];
    float c0v = c0s;
    const float4* vis4 = (const float4*)(vision + (size_t)b * V * CV);
    for (int j = 0; j < 16; j++) {
        int s = wave * 16 + j;
        int row = idxs[s];
        float4 f = vis4[(size_t)row * (CV / 4) + lane];
        float part = f.x * zv.x + f.y * zv.y + f.z * zv.z + f.w * zv.w;
        for (int off = 32; off > 0; off >>= 1) part += __shfl_xor(part, off);
        if (lane == 0) ps[s] = expf((part + c0v) * 0.03125f);
    }
    __syncthreads();
    if (tid < 64) {
        float rs = ps[tid];
        for (int off = 32; off > 0; off >>= 1) rs += __shfl_xor(rs, off);
        if (tid == 0) {
            ws[RS_OFF + bt] = rs;
            atomicAdd(ws + DENOM_OFF + b, rs);
        }
    }
    // w accumulation: thread = cv, coalesced row reads (L2-hot from phase 1)
    float acc = 0.f;
#pragma unroll 4
    for (int s = 0; s < S; s++)
        acc += ps[s] * vision[((size_t)b * V + idxs[s]) * CV + tid];
    ws[W_OFF + (size_t)bt * CV + tid] = acc;
}

// ---- out[bt,d] = x[bt,d] + (sum_cv W[bt,cv]*Wvp[cv,d] + rs[bt]*bv[d]) / denom[b] ----
__global__ void g_out(const float* __restrict__ x, const float* __restrict__ ws,
                      float* __restrict__ out) {
    __shared__ float As[64][9];
    int mt = blockIdx.x & 127, nt = blockIdx.x >> 7;
    int m0 = mt * 8;
    int n = nt * 256 + threadIdx.x;
    float acc[8] = {0, 0, 0, 0, 0, 0, 0, 0};
    for (int kc = 0; kc < CV; kc += 64) {
        for (int l = threadIdx.x; l < 512; l += 256) {
            int ki = l & 63, mi = l >> 6;
            As[ki][mi] = ws[W_OFF + (size_t)(m0 + mi) * CV + kc + ki];
        }
        __syncthreads();
#pragma unroll 8
        for (int ki = 0; ki < 64; ki++) {
            float bv = ws[WVP_OFF + (size_t)(kc + ki) * DIM + n];
#pragma unroll
            for (int mi = 0; mi < 8; mi++) acc[mi] += As[ki][mi] * bv;
        }
        __syncthreads();
    }
    float bvv = ws[BV_OFF + n];
#pragma unroll
    for (int mi = 0; mi < 8; mi++) {
        int bt = m0 + mi;
        float rs = ws[RS_OFF + bt];
        float inv = 1.0f / ws[DENOM_OFF + (bt >> 8)];
        out[(size_t)bt * DIM + n] = x[(size_t)bt * DIM + n] + (acc[mi] + rs * bvv) * inv;
    }
}

extern "C" void kernel_launch(void* const* d_in, const int* in_sizes, int n_in,
                              void* d_out, int out_size, void* d_ws, size_t ws_size,
                              hipStream_t stream) {
    (void)in_sizes; (void)n_in; (void)out_size; (void)ws_size;
    const float* x      = (const float*)d_in[0];
    const float* vision = (const float*)d_in[1];
    const void*  mask   = d_in[2];
    const float* Wu     = (const float*)d_in[3];
    const float* bu     = (const float*)d_in[4];
    const float* Wk     = (const float*)d_in[5];
    const float* Wv     = (const float*)d_in[6];
    float* out = (float*)d_out;
    float* ws  = (float*)d_ws;
    int*   wsi = (int*)d_ws;

    hipMemsetAsync((char*)d_ws + (size_t)DENOM_OFF * 4, 0,
                   (size_t)(WS_TOTAL - DENOM_OFF) * 4, stream);

    detect_mask_mode<<<256, 256, 0, stream>>>((const uint8_t*)mask, B * V * T,
                                              wsi + FLAGA_OFF, wsi + FLAGB_OFF);
    count_chunks<<<B * 16, 256, 0, stream>>>(mask, wsi);
    write_idx<<<B * 16, 256, 0, stream>>>(mask, wsi);
    g_prep<<<256, 256, 0, stream>>>(Wu, Wk, Wv, ws);
    prep_bias<<<8, 256, 0, stream>>>(bu, Wk, Wv, ws);
    g_z<<<128, 256, 0, stream>>>(x, ws);
    g_k3<<<B * T, 256, 0, stream>>>(vision, ws, wsi);
    g_out<<<512, 256, 0, stream>>>(x, ws, out);
}

// Round 4
// 215.523 us; speedup vs baseline: 6.7630x; 1.4369x over previous
//
#include <hip/hip_runtime.h>
#include <stdint.h>

#define B 4
#define T 256
#define V 1024
#define S 64
#define DIM 1024
#define CV 256

typedef __attribute__((ext_vector_type(8))) short bf16x8;
typedef __attribute__((ext_vector_type(4))) short s16x4;
typedef __attribute__((ext_vector_type(4))) float f32x4;

// ---- workspace layout (4-byte word offsets; bf16 arrays counted in words) ----
enum : int {
    REG_A   = 0,                  // [524288 w] WkT bf16 [DIM][DIM]; later XB bf16 [B*T][DIM]
    REG_B   = 524288,             // [524288 w] WvT bf16 [DIM][DIM]; later Z/WB/C0/RS
    WUB_O   = 1048576,            // [131072 w] Wu bf16 [CV][DIM]
    WKPB_O  = WUB_O + 131072,     // [131072 w] Wkp bf16 [CV][DIM]   (B^T for g_z)
    WVPT_O  = WKPB_O + 131072,    // [131072 w] WvpT bf16 [DIM][CV]  (B^T for g_out)
    BK_O    = WVPT_O + 131072,    // [DIM] f32 bu@Wk
    BV_O    = BK_O + DIM,         // [DIM] f32 bu@Wv
    PIDX_O  = BV_O + DIM,         // [B*T*S] int
    CNT_O   = PIDX_O + B*T*S,     // [B*T*16] int
    DENOM_O = CNT_O + B*T*16,     // [B] f32 (zeroed)
    FLAGA_O = DENOM_O + B,        // [1] (zeroed)
    FLAGB_O = FLAGA_O + 1,        // [1] (zeroed)
    WS_TOTAL= FLAGB_O + 1,
    // REG_B sub-offsets (live after g_prep consumed WvT):
    Z_O     = REG_B,              // [B*T*CV] f32
    WB_O    = REG_B + 262144,     // [131072 w] W bf16 [B*T][CV]
    C0_O    = REG_B + 393216,     // [B*T] f32
    RS_O    = C0_O + B*T          // [B*T] f32
};

__device__ __forceinline__ short f2bf(float f) {
    union { float f; unsigned u; } x; x.f = f;
    unsigned r = (x.u + 0x7FFF + ((x.u >> 16) & 1)) >> 16;
    return (short)r;
}

// ---- sniff mask encoding: int32/f32 (4-byte) vs uint8 ----
__global__ void detect_mask_mode(const uint8_t* __restrict__ m, int nbytes,
                                 int* __restrict__ flagA, int* __restrict__ flagB) {
    int i = blockIdx.x * blockDim.x + threadIdx.x;
    int stride = gridDim.x * blockDim.x;
    int a = 0, bfl = 0;
    for (; i < nbytes; i += stride) {
        uint8_t v = m[i];
        if (v) {
            if (i & 3) a = 1;
            if (v == 0x3f) bfl = 1;
        }
    }
    if (a) *flagA = 1;
    if (bfl) *flagB = 1;
}

// ---- phase 1: count set mask bits per (b,t,chunk-of-64-v); coalesced in t ----
__global__ void count_chunks(const void* __restrict__ maskp, int* __restrict__ wsi) {
    int blk = blockIdx.x;
    int b = blk >> 4, c = blk & 15;
    int t = threadIdx.x;
    bool byteMode = (wsi[FLAGA_O] && !wsi[FLAGB_O]);
    int v0 = c * 64;
    int cnt = 0;
    if (byteMode) {
        const uint8_t* m = (const uint8_t*)maskp + (size_t)(b * V + v0) * T + t;
#pragma unroll 8
        for (int j = 0; j < 64; j++) cnt += (m[(size_t)j * T] != 0);
    } else {
        const int* m = (const int*)maskp + (size_t)(b * V + v0) * T + t;
#pragma unroll 8
        for (int j = 0; j < 64; j++) cnt += (m[(size_t)j * T] != 0);
    }
    wsi[CNT_O + (b * T + t) * 16 + c] = cnt;
}

// ---- phase 2: rescan chunk, scatter indices at prefix offset ----
__global__ void write_idx(const void* __restrict__ maskp, int* __restrict__ wsi) {
    int blk = blockIdx.x;
    int b = blk >> 4, c = blk & 15;
    int t = threadIdx.x;
    bool byteMode = (wsi[FLAGA_O] && !wsi[FLAGB_O]);
    int bt = b * T + t;
    int off = 0, total = 0;
#pragma unroll
    for (int cc = 0; cc < 16; cc++) {
        int cn = wsi[CNT_O + bt * 16 + cc];
        if (cc < c) off += cn;
        total += cn;
    }
    int base = PIDX_O + bt * S;
    int v0 = c * 64;
    if (byteMode) {
        const uint8_t* m = (const uint8_t*)maskp + (size_t)(b * V + v0) * T + t;
        for (int j = 0; j < 64; j++)
            if (m[(size_t)j * T] != 0) { if (off < S) wsi[base + off] = v0 + j; off++; }
    } else {
        const int* m = (const int*)maskp + (size_t)(b * V + v0) * T + t;
        for (int j = 0; j < 64; j++)
            if (m[(size_t)j * T] != 0) { if (off < S) wsi[base + off] = v0 + j; off++; }
    }
    if (c == 15)
        for (int j = (total < S ? total : S); j < S; j++) wsi[base + j] = 0;
}

// ---- convert Wu f32 [CV][DIM] -> bf16 straight ----
__global__ void conv_wu(const float* __restrict__ Wu, float* __restrict__ ws) {
    short* wub = (short*)(ws + WUB_O);
    int i = (blockIdx.x * 256 + threadIdx.x) * 4;
    float4 f = *(const float4*)(Wu + i);
    s16x4 o;
    o.x = f2bf(f.x); o.y = f2bf(f.y); o.z = f2bf(f.z); o.w = f2bf(f.w);
    *(s16x4*)(wub + i) = o;
}

// ---- transpose-convert Wk/Wv f32 [e][d] -> bf16 [d][e] via LDS tile ----
__global__ void conv_tr(const float* __restrict__ Wk, const float* __restrict__ Wv,
                        float* __restrict__ ws) {
    __shared__ short lds[64 * 65];
    int which = blockIdx.x >> 8, tile = blockIdx.x & 255;
    int e0 = (tile >> 4) * 64, d0 = (tile & 15) * 64;
    const float* src = which ? Wv : Wk;
    short* dst = (short*)(ws + (which ? REG_B : REG_A));
    int j = threadIdx.x & 63;
    int i0 = threadIdx.x >> 6;
#pragma unroll
    for (int p = 0; p < 16; p++) {
        int i = p * 4 + i0;
        lds[j * 65 + i] = f2bf(src[(size_t)(e0 + i) * DIM + d0 + j]);
    }
    __syncthreads();
#pragma unroll
    for (int p = 0; p < 16; p++) {
        int dd = p * 4 + i0;
        dst[(size_t)(d0 + dd) * DIM + e0 + j] = lds[dd * 65 + j];
    }
}

// ---- bk = bu@Wk, bv = bu@Wv (f32, exact) ----
__global__ void prep_bias(const float* __restrict__ bu, const float* __restrict__ Wk,
                          const float* __restrict__ Wv, float* __restrict__ ws) {
    int which = blockIdx.x >> 2;
    int d = (blockIdx.x & 3) * 256 + threadIdx.x;
    const float* Wsel = which ? Wv : Wk;
    float acc = 0.f;
    for (int e = 0; e < DIM; e++) acc += bu[e] * Wsel[(size_t)e * DIM + d];
    ws[(which ? BV_O : BK_O) + d] = acc;
}

// ---- convert x -> bf16 (over dead WkT region) and c0[bt] = x[bt].bk ----
__global__ void conv_x_c0(const float* __restrict__ x, float* __restrict__ ws) {
    __shared__ float red[256];
    short* xb = (short*)(ws + REG_A);
    int bt = blockIdx.x;
    int i = threadIdx.x * 4;
    float4 f = *(const float4*)(x + (size_t)bt * DIM + i);
    s16x4 o;
    o.x = f2bf(f.x); o.y = f2bf(f.y); o.z = f2bf(f.z); o.w = f2bf(f.w);
    *(s16x4*)(xb + (size_t)bt * DIM + i) = o;
    float d = f.x * ws[BK_O + i] + f.y * ws[BK_O + i + 1] +
              f.z * ws[BK_O + i + 2] + f.w * ws[BK_O + i + 3];
    red[threadIdx.x] = d;
    __syncthreads();
    for (int s2 = 128; s2 > 0; s2 >>= 1) {
        if (threadIdx.x < s2) red[threadIdx.x] += red[threadIdx.x + s2];
        __syncthreads();
    }
    if (threadIdx.x == 0) ws[C0_O + bt] = red[0];
}

// ---- per-wave 32x32 MFMA tile: A[m][k] row-major, Bt[n][k] row-major ----
template<int K, int LDA, int LDB>
__device__ __forceinline__ void wave_mma(const short* __restrict__ A0,
                                         const short* __restrict__ B0,
                                         f32x4 acc[2][2]) {
    int lane = threadIdx.x & 63;
    int rw = lane & 15, q = lane >> 4;
    const short* ap0 = A0 + rw * LDA + q * 8;
    const short* ap1 = ap0 + 16 * LDA;
    const short* bp0 = B0 + rw * LDB + q * 8;
    const short* bp1 = bp0 + 16 * LDB;
#pragma unroll 4
    for (int kc = 0; kc < K; kc += 32) {
        bf16x8 a0 = *(const bf16x8*)(ap0 + kc);
        bf16x8 a1 = *(const bf16x8*)(ap1 + kc);
        bf16x8 b0 = *(const bf16x8*)(bp0 + kc);
        bf16x8 b1 = *(const bf16x8*)(bp1 + kc);
        acc[0][0] = __builtin_amdgcn_mfma_f32_16x16x32_bf16(a0, b0, acc[0][0], 0, 0, 0);
        acc[0][1] = __builtin_amdgcn_mfma_f32_16x16x32_bf16(a0, b1, acc[0][1], 0, 0, 0);
        acc[1][0] = __builtin_amdgcn_mfma_f32_16x16x32_bf16(a1, b0, acc[1][0], 0, 0, 0);
        acc[1][1] = __builtin_amdgcn_mfma_f32_16x16x32_bf16(a1, b1, acc[1][1], 0, 0, 0);
    }
}

// ---- Wkp = Wu@Wk (bf16 out, [cv][d]) and WvpT = (Wu@Wv)^T (bf16 out, [d][cv]) ----
__global__ void g_prep_mfma(float* __restrict__ ws) {
    int w = blockIdx.x * 4 + (threadIdx.x >> 6);   // 512 wave-tiles
    int which = w >> 8, rem = w & 255;
    int m0 = (rem >> 5) * 32, n0 = (rem & 31) * 32;   // m: cv(256), n: d(1024)
    const short* A = (const short*)(ws + WUB_O) + (size_t)m0 * DIM;
    const short* Bt = (const short*)(ws + (which ? REG_B : REG_A)) + (size_t)n0 * DIM;
    f32x4 acc[2][2] = {};
    wave_mma<DIM, DIM, DIM>(A, Bt, acc);
    int lane = threadIdx.x & 63, col = lane & 15, q = lane >> 4;
    if (which == 0) {
        short* out = (short*)(ws + WKPB_O);
#pragma unroll
        for (int i = 0; i < 2; i++)
#pragma unroll
            for (int j = 0; j < 2; j++)
#pragma unroll
                for (int r = 0; r < 4; r++)
                    out[(size_t)(m0 + i * 16 + q * 4 + r) * DIM + n0 + j * 16 + col] =
                        f2bf(acc[i][j][r]);
    } else {
        short* out = (short*)(ws + WVPT_O);
#pragma unroll
        for (int i = 0; i < 2; i++)
#pragma unroll
            for (int j = 0; j < 2; j++) {
                s16x4 v;
                v.x = f2bf(acc[i][j][0]); v.y = f2bf(acc[i][j][1]);
                v.z = f2bf(acc[i][j][2]); v.w = f2bf(acc[i][j][3]);
                *(s16x4*)&out[(size_t)(n0 + j * 16 + col) * CV + m0 + i * 16 + q * 4] = v;
            }
    }
}

// ---- Z[bt][cv] f32 = Xb @ Wkp^T ----
__global__ void g_z_mfma(float* __restrict__ ws) {
    int w = blockIdx.x * 4 + (threadIdx.x >> 6);   // 256 wave-tiles
    int m0 = (w >> 3) * 32, n0 = (w & 7) * 32;     // m: bt(1024), n: cv(256)
    const short* A = (const short*)(ws + REG_A) + (size_t)m0 * DIM;
    const short* Bt = (const short*)(ws + WKPB_O) + (size_t)n0 * DIM;
    f32x4 acc[2][2] = {};
    wave_mma<DIM, DIM, DIM>(A, Bt, acc);
    int lane = threadIdx.x & 63, col = lane & 15, q = lane >> 4;
#pragma unroll
    for (int i = 0; i < 2; i++)
#pragma unroll
        for (int j = 0; j < 2; j++)
#pragma unroll
            for (int r = 0; r < 4; r++)
                ws[Z_O + (size_t)(m0 + i * 16 + q * 4 + r) * CV + n0 + j * 16 + col] =
                    acc[i][j][r];
}

// ---- per (b,t): p_s = exp((vision_row_s . z + c0)/32); W bf16 = sum p_s*row_s ----
__global__ void g_k3(const float* __restrict__ vision, float* __restrict__ ws,
                     int* __restrict__ wsi) {
    __shared__ float zs[CV];
    __shared__ float ps[S];
    __shared__ int idxs[S];
    __shared__ float c0s;
    int bt = blockIdx.x, b = bt >> 8;
    int tid = threadIdx.x;
    zs[tid] = ws[Z_O + (size_t)bt * CV + tid];
    if (tid < S) idxs[tid] = wsi[PIDX_O + bt * S + tid];
    if (tid == 0) c0s = ws[C0_O + bt];
    __syncthreads();
    int wave = tid >> 6, lane = tid & 63;
    float4 zv = ((const float4*)zs)[lane];
    float c0v = c0s;
    const float4* vis4 = (const float4*)(vision + (size_t)b * V * CV);
    for (int j = 0; j < 16; j++) {
        int s = wave * 16 + j;
        int row = idxs[s];
        float4 f = vis4[(size_t)row * (CV / 4) + lane];
        float part = f.x * zv.x + f.y * zv.y + f.z * zv.z + f.w * zv.w;
        for (int off = 32; off > 0; off >>= 1) part += __shfl_xor(part, off);
        if (lane == 0) ps[s] = expf((part + c0v) * 0.03125f);
    }
    __syncthreads();
    if (tid < 64) {
        float rs = ps[tid];
        for (int off = 32; off > 0; off >>= 1) rs += __shfl_xor(rs, off);
        if (tid == 0) {
            ws[RS_O + bt] = rs;
            atomicAdd(ws + DENOM_O + b, rs);
        }
    }
    float acc = 0.f;
#pragma unroll 4
    for (int s = 0; s < S; s++)
        acc += ps[s] * vision[((size_t)b * V + idxs[s]) * CV + tid];
    ((short*)(ws + WB_O))[(size_t)bt * CV + tid] = f2bf(acc);
}

// ---- out[bt][d] = x + (Wb @ WvpT^T + rs*bv) / denom ----
__global__ void g_out_mfma(const float* __restrict__ x, float* __restrict__ ws,
                           float* __restrict__ out) {
    int w = blockIdx.x * 4 + (threadIdx.x >> 6);   // 1024 wave-tiles
    int m0 = (w >> 5) * 32, n0 = (w & 31) * 32;    // m: bt(1024), n: d(1024)
    const short* A = (const short*)(ws + WB_O) + (size_t)m0 * CV;
    const short* Bt = (const short*)(ws + WVPT_O) + (size_t)n0 * CV;
    f32x4 acc[2][2] = {};
    wave_mma<CV, CV, CV>(A, Bt, acc);
    int lane = threadIdx.x & 63, col = lane & 15, q = lane >> 4;
#pragma unroll
    for (int i = 0; i < 2; i++)
#pragma unroll
        for (int r = 0; r < 4; r++) {
            int row = m0 + i * 16 + q * 4 + r;
            float rs = ws[RS_O + row];
            float inv = 1.0f / ws[DENOM_O + (row >> 8)];
#pragma unroll
            for (int j = 0; j < 2; j++) {
                int cc = n0 + j * 16 + col;
                out[(size_t)row * DIM + cc] =
                    x[(size_t)row * DIM + cc] + (acc[i][j][r] + rs * ws[BV_O + cc]) * inv;
            }
        }
}

extern "C" void kernel_launch(void* const* d_in, const int* in_sizes, int n_in,
                              void* d_out, int out_size, void* d_ws, size_t ws_size,
                              hipStream_t stream) {
    (void)in_sizes; (void)n_in; (void)out_size; (void)ws_size;
    const float* x      = (const float*)d_in[0];
    const float* vision = (const float*)d_in[1];
    const void*  mask   = d_in[2];
    const float* Wu     = (const float*)d_in[3];
    const float* bu     = (const float*)d_in[4];
    const float* Wk     = (const float*)d_in[5];
    const float* Wv     = (const float*)d_in[6];
    float* out = (float*)d_out;
    float* ws  = (float*)d_ws;
    int*   wsi = (int*)d_ws;

    hipMemsetAsync((char*)d_ws + (size_t)DENOM_O * 4, 0,
                   (size_t)(WS_TOTAL - DENOM_O) * 4, stream);

    detect_mask_mode<<<256, 256, 0, stream>>>((const uint8_t*)mask, B * V * T,
                                              wsi + FLAGA_O, wsi + FLAGB_O);
    count_chunks<<<B * 16, 256, 0, stream>>>(mask, wsi);
    write_idx<<<B * 16, 256, 0, stream>>>(mask, wsi);
    conv_wu<<<256, 256, 0, stream>>>(Wu, ws);
    conv_tr<<<512, 256, 0, stream>>>(Wk, Wv, ws);
    prep_bias<<<8, 256, 0, stream>>>(bu, Wk, Wv, ws);
    g_prep_mfma<<<128, 256, 0, stream>>>(ws);
    conv_x_c0<<<B * T, 256, 0, stream>>>(x, ws);   // after g_prep: overwrites WkT/WvT tails
    g_z_mfma<<<64, 256, 0, stream>>>(ws);
    g_k3<<<B * T, 256, 0, stream>>>(vision, ws, wsi);
    g_out_mfma<<<256, 256, 0, stream>>>(x, ws, out);
}

// Round 5
// 184.463 us; speedup vs baseline: 7.9017x; 1.1684x over previous
//
#include <hip/hip_runtime.h>
#include <stdint.h>

#define B 4
#define T 256
#define V 1024
#define S 64
#define DIM 1024
#define CV 256

typedef __attribute__((ext_vector_type(8))) short bf16x8;
typedef __attribute__((ext_vector_type(4))) short s16x4;
typedef __attribute__((ext_vector_type(4))) float f32x4;

// ---- workspace layout (4-byte word offsets; bf16 arrays counted in words) ----
enum : int {
    WKT_O   = 0,                  // [262144 w] WkT bf16 [DIM][DIM] (d-major)
    WVT_O   = WKT_O + 262144,     // [262144 w] WvT bf16 [DIM][DIM]
    WUB_O   = WVT_O + 262144,     // [131072 w] Wu bf16 [CV][DIM]
    WKPB_O  = WUB_O + 131072,     // [131072 w] Wkp bf16 [CV][DIM]   (B^T for g_z)
    WVPT_O  = WKPB_O + 131072,    // [131072 w] WvpT bf16 [DIM][CV]  (B^T for g_out)
    XB_O    = WVPT_O + 131072,    // [262144 w] x bf16 [B*T][DIM]
    ZB_O    = XB_O + 262144,      // [131072 w] Z bf16 [B*T][CV]
    VB_O    = ZB_O + 131072,      // [524288 w] vision bf16 [B][V][CV]
    SC_O    = VB_O + 524288,      // [B*T*V] f32 scores
    WB_O    = SC_O + B*T*V,       // [131072 w] W bf16 [B*T][CV]
    C0_O    = WB_O + 131072,      // [B*T] f32 bk.x
    RS_O    = C0_O + B*T,         // [B*T] f32 row sums
    PIDX_O  = RS_O + B*T,         // [B*T*S] int selected v
    BK_O    = PIDX_O + B*T*S,     // [DIM] f32 bu@Wk   (zeroed, atomic target)
    BV_O    = BK_O + DIM,         // [DIM] f32 bu@Wv   (zeroed, atomic target)
    DENOM_O = BV_O + DIM,         // [B]   f32         (zeroed)
    FLAGA_O = DENOM_O + B,        // [1]               (zeroed)
    FLAGB_O = FLAGA_O + 1,        // [1]               (zeroed)
    WS_TOTAL= FLAGB_O + 1
};

__device__ __forceinline__ short f2bf(float f) {
    union { float f; unsigned u; } x; x.f = f;
    unsigned r = (x.u + 0x7FFF + ((x.u >> 16) & 1)) >> 16;
    return (short)r;
}

// ---- sniff mask encoding: int32/f32 (4-byte) vs uint8 ----
__global__ void detect_mask_mode(const uint8_t* __restrict__ m, int nbytes,
                                 int* __restrict__ flagA, int* __restrict__ flagB) {
    int i = blockIdx.x * blockDim.x + threadIdx.x;
    int stride = gridDim.x * blockDim.x;
    int a = 0, bfl = 0;
    for (; i < nbytes; i += stride) {
        uint8_t v = m[i];
        if (v) {
            if (i & 3) a = 1;
            if (v == 0x3f) bfl = 1;
        }
    }
    if (a) *flagA = 1;
    if (bfl) *flagB = 1;
}

// ---- fused count+prefix+scatter: grid B*16 (t-groups of 16), 256 thr = 16t x 16c ----
__global__ void mask_compact(const void* __restrict__ maskp, int* __restrict__ wsi) {
    __shared__ int cnt[16][17];
    int b = blockIdx.x >> 4, tg = blockIdx.x & 15;
    int tl = threadIdx.x & 15;       // t within group
    int c  = threadIdx.x >> 4;       // chunk of 64 v's
    int t  = tg * 16 + tl;
    bool byteMode = (wsi[FLAGA_O] && !wsi[FLAGB_O]);
    int v0 = c * 64;
    int n = 0;
    if (byteMode) {
        const uint8_t* m = (const uint8_t*)maskp + (size_t)(b * V + v0) * T + t;
#pragma unroll 8
        for (int j = 0; j < 64; j++) n += (m[(size_t)j * T] != 0);
    } else {
        const int* m = (const int*)maskp + (size_t)(b * V + v0) * T + t;
#pragma unroll 8
        for (int j = 0; j < 64; j++) n += (m[(size_t)j * T] != 0);
    }
    cnt[tl][c] = n;
    __syncthreads();
    int off = 0, total = 0;
#pragma unroll
    for (int cc = 0; cc < 16; cc++) {
        int cn = cnt[tl][cc];
        if (cc < c) off += cn;
        total += cn;
    }
    int base = PIDX_O + (b * T + t) * S;
    if (byteMode) {
        const uint8_t* m = (const uint8_t*)maskp + (size_t)(b * V + v0) * T + t;
        for (int j = 0; j < 64; j++)
            if (m[(size_t)j * T] != 0) { if (off < S) wsi[base + off] = v0 + j; off++; }
    } else {
        const int* m = (const int*)maskp + (size_t)(b * V + v0) * T + t;
        for (int j = 0; j < 64; j++)
            if (m[(size_t)j * T] != 0) { if (off < S) wsi[base + off] = v0 + j; off++; }
    }
    if (c == 15)
        for (int j = (total < S ? total : S); j < S; j++) wsi[base + j] = 0;
}

// ---- convert Wu f32 [CV][DIM] -> bf16 straight ----
__global__ void conv_wu(const float* __restrict__ Wu, float* __restrict__ ws) {
    short* wub = (short*)(ws + WUB_O);
    int i = (blockIdx.x * 256 + threadIdx.x) * 4;
    float4 f = *(const float4*)(Wu + i);
    s16x4 o;
    o.x = f2bf(f.x); o.y = f2bf(f.y); o.z = f2bf(f.z); o.w = f2bf(f.w);
    *(s16x4*)(wub + i) = o;
}

// ---- convert vision f32 -> bf16 straight ----
__global__ void conv_vis(const float* __restrict__ vis, float* __restrict__ ws) {
    short* vb = (short*)(ws + VB_O);
    int i = (blockIdx.x * 256 + threadIdx.x) * 4;
    float4 f = *(const float4*)(vis + i);
    s16x4 o;
    o.x = f2bf(f.x); o.y = f2bf(f.y); o.z = f2bf(f.z); o.w = f2bf(f.w);
    *(s16x4*)(vb + i) = o;
}

// ---- transpose-convert Wk/Wv -> bf16 [d][e]; fused bk/bv partial via atomics ----
__global__ void conv_tr_bias(const float* __restrict__ Wk, const float* __restrict__ Wv,
                             const float* __restrict__ bu, float* __restrict__ ws) {
    __shared__ short lds[64 * 65];
    __shared__ float red[4 * 64];
    int which = blockIdx.x >> 8, tile = blockIdx.x & 255;
    int e0 = (tile >> 4) * 64, d0 = (tile & 15) * 64;
    const float* src = which ? Wv : Wk;
    short* dst = (short*)(ws + (which ? WVT_O : WKT_O));
    int j = threadIdx.x & 63;       // d-local
    int i0 = threadIdx.x >> 6;      // e-group
    float pb = 0.f;
#pragma unroll
    for (int p = 0; p < 16; p++) {
        int i = p * 4 + i0;
        float v = src[(size_t)(e0 + i) * DIM + d0 + j];
        lds[j * 65 + i] = f2bf(v);
        pb += bu[e0 + i] * v;
    }
    red[i0 * 64 + j] = pb;
    __syncthreads();
#pragma unroll
    for (int p = 0; p < 16; p++) {
        int dd = p * 4 + i0;
        dst[(size_t)(d0 + dd) * DIM + e0 + j] = lds[dd * 65 + j];
    }
    if (i0 == 0) {
        float s = red[j] + red[64 + j] + red[128 + j] + red[192 + j];
        atomicAdd(ws + (which ? BV_O : BK_O) + d0 + j, s);
    }
}

// ---- convert x -> bf16 and c0[bt] = x[bt].bk (needs bk complete) ----
__global__ void conv_x_c0(const float* __restrict__ x, float* __restrict__ ws) {
    __shared__ float red[256];
    short* xb = (short*)(ws + XB_O);
    int bt = blockIdx.x;
    int i = threadIdx.x * 4;
    float4 f = *(const float4*)(x + (size_t)bt * DIM + i);
    s16x4 o;
    o.x = f2bf(f.x); o.y = f2bf(f.y); o.z = f2bf(f.z); o.w = f2bf(f.w);
    *(s16x4*)(xb + (size_t)bt * DIM + i) = o;
    float d = f.x * ws[BK_O + i] + f.y * ws[BK_O + i + 1] +
              f.z * ws[BK_O + i + 2] + f.w * ws[BK_O + i + 3];
    red[threadIdx.x] = d;
    __syncthreads();
    for (int s2 = 128; s2 > 0; s2 >>= 1) {
        if (threadIdx.x < s2) red[threadIdx.x] += red[threadIdx.x + s2];
        __syncthreads();
    }
    if (threadIdx.x == 0) ws[C0_O + bt] = red[0];
}

// ---- per-wave 32x32 MFMA tile: A[m][k] row-major, Bt[n][k] row-major ----
template<int K, int LDA, int LDB>
__device__ __forceinline__ void wave_mma(const short* __restrict__ A0,
                                         const short* __restrict__ B0,
                                         f32x4 acc[2][2]) {
    int lane = threadIdx.x & 63;
    int rw = lane & 15, q = lane >> 4;
    const short* ap0 = A0 + rw * LDA + q * 8;
    const short* ap1 = ap0 + 16 * LDA;
    const short* bp0 = B0 + rw * LDB + q * 8;
    const short* bp1 = bp0 + 16 * LDB;
#pragma unroll 4
    for (int kc = 0; kc < K; kc += 32) {
        bf16x8 a0 = *(const bf16x8*)(ap0 + kc);
        bf16x8 a1 = *(const bf16x8*)(ap1 + kc);
        bf16x8 b0 = *(const bf16x8*)(bp0 + kc);
        bf16x8 b1 = *(const bf16x8*)(bp1 + kc);
        acc[0][0] = __builtin_amdgcn_mfma_f32_16x16x32_bf16(a0, b0, acc[0][0], 0, 0, 0);
        acc[0][1] = __builtin_amdgcn_mfma_f32_16x16x32_bf16(a0, b1, acc[0][1], 0, 0, 0);
        acc[1][0] = __builtin_amdgcn_mfma_f32_16x16x32_bf16(a1, b0, acc[1][0], 0, 0, 0);
        acc[1][1] = __builtin_amdgcn_mfma_f32_16x16x32_bf16(a1, b1, acc[1][1], 0, 0, 0);
    }
}

// ---- Wkp = Wu@Wk (bf16 [cv][d]) and WvpT = (Wu@Wv)^T (bf16 [d][cv]) ----
__global__ void g_prep_mfma(float* __restrict__ ws) {
    int w = blockIdx.x * 4 + (threadIdx.x >> 6);     // 512 wave-tiles
    int which = w >> 8, rem = w & 255;
    int m0 = (rem >> 5) * 32, n0 = (rem & 31) * 32;  // m: cv(256), n: d(1024)
    const short* A = (const short*)(ws + WUB_O) + (size_t)m0 * DIM;
    const short* Bt = (const short*)(ws + (which ? WVT_O : WKT_O)) + (size_t)n0 * DIM;
    f32x4 acc[2][2] = {};
    wave_mma<DIM, DIM, DIM>(A, Bt, acc);
    int lane = threadIdx.x & 63, col = lane & 15, q = lane >> 4;
    if (which == 0) {
        short* out = (short*)(ws + WKPB_O);
#pragma unroll
        for (int i = 0; i < 2; i++)
#pragma unroll
            for (int j = 0; j < 2; j++)
#pragma unroll
                for (int r = 0; r < 4; r++)
                    out[(size_t)(m0 + i * 16 + q * 4 + r) * DIM + n0 + j * 16 + col] =
                        f2bf(acc[i][j][r]);
    } else {
        short* out = (short*)(ws + WVPT_O);
#pragma unroll
        for (int i = 0; i < 2; i++)
#pragma unroll
            for (int j = 0; j < 2; j++) {
                s16x4 v;
                v.x = f2bf(acc[i][j][0]); v.y = f2bf(acc[i][j][1]);
                v.z = f2bf(acc[i][j][2]); v.w = f2bf(acc[i][j][3]);
                *(s16x4*)&out[(size_t)(n0 + j * 16 + col) * CV + m0 + i * 16 + q * 4] = v;
            }
    }
}

// ---- Z bf16 [bt][cv] = Xb @ Wkp^T ----
__global__ void g_z_mfma(float* __restrict__ ws) {
    int w = blockIdx.x * 4 + (threadIdx.x >> 6);   // 256 wave-tiles
    int m0 = (w >> 3) * 32, n0 = (w & 7) * 32;     // m: bt(1024), n: cv(256)
    const short* A = (const short*)(ws + XB_O) + (size_t)m0 * DIM;
    const short* Bt = (const short*)(ws + WKPB_O) + (size_t)n0 * DIM;
    f32x4 acc[2][2] = {};
    wave_mma<DIM, DIM, DIM>(A, Bt, acc);
    int lane = threadIdx.x & 63, col = lane & 15, q = lane >> 4;
    short* zb = (short*)(ws + ZB_O);
#pragma unroll
    for (int i = 0; i < 2; i++)
#pragma unroll
        for (int j = 0; j < 2; j++)
#pragma unroll
            for (int r = 0; r < 4; r++)
                zb[(size_t)(m0 + i * 16 + q * 4 + r) * CV + n0 + j * 16 + col] =
                    f2bf(acc[i][j][r]);
}

// ---- Sc f32 [b][t][v] = Z_b @ vision_b^T ----
__global__ void g_sc_mfma(float* __restrict__ ws) {
    int w = blockIdx.x * 4 + (threadIdx.x >> 6);   // 1024 wave-tiles
    int b = w >> 8, rem = w & 255;
    int m0 = (rem >> 5) * 32, n0 = (rem & 31) * 32;  // m: t(256), n: v(1024)
    const short* A = (const short*)(ws + ZB_O) + (size_t)(b * T + m0) * CV;
    const short* Bt = (const short*)(ws + VB_O) + (size_t)(b * V + n0) * CV;
    f32x4 acc[2][2] = {};
    wave_mma<CV, CV, CV>(A, Bt, acc);
    int lane = threadIdx.x & 63, col = lane & 15, q = lane >> 4;
#pragma unroll
    for (int i = 0; i < 2; i++)
#pragma unroll
        for (int j = 0; j < 2; j++)
#pragma unroll
            for (int r = 0; r < 4; r++)
                ws[SC_O + (size_t)(b * T + m0 + i * 16 + q * 4 + r) * V +
                   n0 + j * 16 + col] = acc[i][j][r];
}

// ---- per (b,t): gather 64 scores, exp, rs/denom, W bf16 = sum p_s*row_s ----
__global__ void g_k3w(const float* __restrict__ vision, float* __restrict__ ws,
                      int* __restrict__ wsi) {
    __shared__ float ps[S];
    __shared__ int idxs[S];
    int bt = blockIdx.x, b = bt >> 8;
    int tid = threadIdx.x;
    if (tid < S) {
        int idx = wsi[PIDX_O + bt * S + tid];
        idxs[tid] = idx;
        float c0 = ws[C0_O + bt];
        float p = expf((ws[SC_O + (size_t)bt * V + idx] + c0) * 0.03125f);
        ps[tid] = p;
        for (int off = 32; off > 0; off >>= 1) p += __shfl_xor(p, off);
        if (tid == 0) {
            ws[RS_O + bt] = p;
            atomicAdd(ws + DENOM_O + b, p);
        }
    }
    __syncthreads();
    float acc = 0.f;
#pragma unroll 8
    for (int s = 0; s < S; s++)
        acc += ps[s] * vision[((size_t)b * V + idxs[s]) * CV + tid];
    ((short*)(ws + WB_O))[(size_t)bt * CV + tid] = f2bf(acc);
}

// ---- out[bt][d] = x + (Wb @ WvpT^T + rs*bv) / denom ----
__global__ void g_out_mfma(const float* __restrict__ x, float* __restrict__ ws,
                           float* __restrict__ out) {
    int w = blockIdx.x * 4 + (threadIdx.x >> 6);   // 1024 wave-tiles
    int m0 = (w >> 5) * 32, n0 = (w & 31) * 32;    // m: bt(1024), n: d(1024)
    const short* A = (const short*)(ws + WB_O) + (size_t)m0 * CV;
    const short* Bt = (const short*)(ws + WVPT_O) + (size_t)n0 * CV;
    f32x4 acc[2][2] = {};
    wave_mma<CV, CV, CV>(A, Bt, acc);
    int lane = threadIdx.x & 63, col = lane & 15, q = lane >> 4;
#pragma unroll
    for (int i = 0; i < 2; i++)
#pragma unroll
        for (int r = 0; r < 4; r++) {
            int row = m0 + i * 16 + q * 4 + r;
            float rs = ws[RS_O + row];
            float inv = 1.0f / ws[DENOM_O + (row >> 8)];
#pragma unroll
            for (int j = 0; j < 2; j++) {
                int cc = n0 + j * 16 + col;
                out[(size_t)row * DIM + cc] =
                    x[(size_t)row * DIM + cc] + (acc[i][j][r] + rs * ws[BV_O + cc]) * inv;
            }
        }
}

extern "C" void kernel_launch(void* const* d_in, const int* in_sizes, int n_in,
                              void* d_out, int out_size, void* d_ws, size_t ws_size,
                              hipStream_t stream) {
    (void)in_sizes; (void)n_in; (void)out_size; (void)ws_size;
    const float* x      = (const float*)d_in[0];
    const float* vision = (const float*)d_in[1];
    const void*  mask   = d_in[2];
    const float* Wu     = (const float*)d_in[3];
    const float* bu     = (const float*)d_in[4];
    const float* Wk     = (const float*)d_in[5];
    const float* Wv     = (const float*)d_in[6];
    float* out = (float*)d_out;
    float* ws  = (float*)d_ws;
    int*   wsi = (int*)d_ws;

    // zero bk/bv (atomic targets) + denom + flags
    hipMemsetAsync((char*)d_ws + (size_t)BK_O * 4, 0,
                   (size_t)(WS_TOTAL - BK_O) * 4, stream);

    detect_mask_mode<<<256, 256, 0, stream>>>((const uint8_t*)mask, B * V * T,
                                              wsi + FLAGA_O, wsi + FLAGB_O);
    mask_compact<<<B * 16, 256, 0, stream>>>(mask, wsi);
    conv_wu<<<256, 256, 0, stream>>>(Wu, ws);
    conv_tr_bias<<<512, 256, 0, stream>>>(Wk, Wv, bu, ws);
    conv_vis<<<1024, 256, 0, stream>>>(vision, ws);
    g_prep_mfma<<<128, 256, 0, stream>>>(ws);
    conv_x_c0<<<B * T, 256, 0, stream>>>(x, ws);
    g_z_mfma<<<64, 256, 0, stream>>>(ws);
    g_sc_mfma<<<256, 256, 0, stream>>>(ws);
    g_k3w<<<B * T, 256, 0, stream>>>(vision, ws, wsi);
    g_out_mfma<<<256, 256, 0, stream>>>(x, ws, out);
}

// Round 6
// 145.992 us; speedup vs baseline: 9.9840x; 1.2635x over previous
//
#include <hip/hip_runtime.h>
#include <stdint.h>

#define B 4
#define T 256
#define V 1024
#define S 64
#define DIM 1024
#define CV 256

typedef __attribute__((ext_vector_type(8))) short bf16x8;
typedef __attribute__((ext_vector_type(4))) short s16x4;
typedef __attribute__((ext_vector_type(4))) float f32x4;

// ---- workspace layout (4-byte word offsets; bf16 arrays counted in words) ----
enum : int {
    WKT_O   = 0,                  // [262144 w] WkT bf16 [DIM][DIM] (d-major)
    WVT_O   = WKT_O + 262144,     // [262144 w] WvT bf16 [DIM][DIM]
    WUB_O   = WVT_O + 262144,     // [131072 w] Wu bf16 [CV][DIM]
    WKPB_O  = WUB_O + 131072,     // [131072 w] Wkp bf16 [CV][DIM]   (B^T for g_z)
    WVPT_O  = WKPB_O + 131072,    // [131072 w] WvpT bf16 [DIM][CV]  (B^T for g_out)
    XB_O    = WVPT_O + 131072,    // [262144 w] x bf16 [B*T][DIM]
    ZB_O    = XB_O + 262144,      // [131072 w] Z bf16 [B*T][CV]
    VB_O    = ZB_O + 131072,      // [524288 w] vision bf16 [B][V][CV]
    WB_O    = VB_O + 524288,      // [131072 w] W bf16 [B*T][CV]
    RS_O    = WB_O + 131072,      // [B*T] f32 row sums
    PIDX_O  = RS_O + B*T,         // [B*T*S] int selected v
    BK_O    = PIDX_O + B*T*S,     // [DIM] f32 bu@Wk  (zeroed, atomic target)
    BV_O    = BK_O + DIM,         // [DIM] f32 bu@Wv  (zeroed, atomic target)
    DENOM_O = BV_O + DIM,         // [B]   f32        (zeroed, atomic target)
    WS_TOTAL= DENOM_O + B
};

__device__ __forceinline__ short f2bf(float f) {
    union { float f; unsigned u; } x; x.f = f;
    unsigned r = (x.u + 0x7FFF + ((x.u >> 16) & 1)) >> 16;
    return (short)r;
}

// ================= stage 1: all input conversion + mask compaction =============
// blocks [0,1024)    : vision f32 -> bf16
// blocks [1024,1280) : Wu f32 -> bf16
// blocks [1280,2304) : x f32 -> bf16
// blocks [2304,2816) : Wk/Wv transpose-convert -> bf16 [d][e] + bk/bv atomics
// blocks [2816,2880) : mask compaction (self-detecting encoding)
__global__ void stage1(const float* __restrict__ vision, const float* __restrict__ Wu,
                       const float* __restrict__ x, const float* __restrict__ Wk,
                       const float* __restrict__ Wv, const float* __restrict__ bu,
                       const void* __restrict__ maskp,
                       float* __restrict__ ws, int* __restrict__ wsi) {
    __shared__ short tlds[64 * 65];
    __shared__ float tred[4 * 64];
    __shared__ int mc_cnt[16][17];
    __shared__ int sa_flag, sb_flag;
    int blk = blockIdx.x;
    int tid = threadIdx.x;

    if (blk < 2304) {  // ---- straight f32 -> bf16 converts ----
        const float* src; short* dst; int idx;
        if (blk < 1024)      { src = vision; dst = (short*)(ws + VB_O);  idx = blk; }
        else if (blk < 1280) { src = Wu;     dst = (short*)(ws + WUB_O); idx = blk - 1024; }
        else                 { src = x;      dst = (short*)(ws + XB_O);  idx = blk - 1280; }
        int i = (idx * 256 + tid) * 4;
        float4 f = *(const float4*)(src + i);
        s16x4 o;
        o.x = f2bf(f.x); o.y = f2bf(f.y); o.z = f2bf(f.z); o.w = f2bf(f.w);
        *(s16x4*)(dst + i) = o;
        return;
    }
    if (blk < 2816) {  // ---- transpose-convert Wk/Wv + fused bias partials ----
        int tile = blk - 2304;
        int which = tile >> 8, t2 = tile & 255;
        int e0 = (t2 >> 4) * 64, d0 = (t2 & 15) * 64;
        const float* src = which ? Wv : Wk;
        short* dst = (short*)(ws + (which ? WVT_O : WKT_O));
        int j = tid & 63;        // d-local
        int i0 = tid >> 6;       // e-group
        float pb = 0.f;
#pragma unroll
        for (int p = 0; p < 16; p++) {
            int i = p * 4 + i0;
            float v = src[(size_t)(e0 + i) * DIM + d0 + j];
            tlds[j * 65 + i] = f2bf(v);
            pb += bu[e0 + i] * v;
        }
        tred[i0 * 64 + j] = pb;
        __syncthreads();
#pragma unroll
        for (int p = 0; p < 16; p++) {
            int dd = p * 4 + i0;
            dst[(size_t)(d0 + dd) * DIM + e0 + j] = tlds[dd * 65 + j];
        }
        if (i0 == 0) {
            float s = tred[j] + tred[64 + j] + tred[128 + j] + tred[192 + j];
            atomicAdd(ws + (which ? BV_O : BK_O) + d0 + j, s);
        }
        return;
    }
    // ---- mask compaction with block-local encoding detection ----
    // detect: scan first 4096 bytes (always within buffer; guaranteed set bits)
    {
        int a = 0, bfl = 0;
        const uchar4* m4 = (const uchar4*)maskp;
#pragma unroll
        for (int jj = 0; jj < 4; jj++) {
            uchar4 u = m4[tid * 4 + jj];
            if (u.y | u.z | u.w) a = 1;
            if (u.x == 0x3f || u.y == 0x3f || u.z == 0x3f || u.w == 0x3f) bfl = 1;
        }
        if (tid == 0) { sa_flag = 0; sb_flag = 0; }
        __syncthreads();
        if (a) sa_flag = 1;       // benign race: same value
        if (bfl) sb_flag = 1;
        __syncthreads();
    }
    bool byteMode = sa_flag && !sb_flag;   // f32 sets both -> 4-byte read path
    int mb = blk - 2816;          // 0..63
    int b = mb >> 4, tg = mb & 15;
    int tl = tid & 15;            // t within group
    int c  = tid >> 4;            // chunk of 64 v's
    int t  = tg * 16 + tl;
    int v0 = c * 64;
    int n = 0;
    if (byteMode) {
        const uint8_t* m = (const uint8_t*)maskp + (size_t)(b * V + v0) * T + t;
#pragma unroll 8
        for (int j = 0; j < 64; j++) n += (m[(size_t)j * T] != 0);
    } else {
        const int* m = (const int*)maskp + (size_t)(b * V + v0) * T + t;
#pragma unroll 8
        for (int j = 0; j < 64; j++) n += (m[(size_t)j * T] != 0);
    }
    mc_cnt[tl][c] = n;
    __syncthreads();
    int off = 0, total = 0;
#pragma unroll
    for (int cc = 0; cc < 16; cc++) {
        int cn = mc_cnt[tl][cc];
        if (cc < c) off += cn;
        total += cn;
    }
    int base = PIDX_O + (b * T + t) * S;
    if (byteMode) {
        const uint8_t* m = (const uint8_t*)maskp + (size_t)(b * V + v0) * T + t;
        for (int j = 0; j < 64; j++)
            if (m[(size_t)j * T] != 0) { if (off < S) wsi[base + off] = v0 + j; off++; }
    } else {
        const int* m = (const int*)maskp + (size_t)(b * V + v0) * T + t;
        for (int j = 0; j < 64; j++)
            if (m[(size_t)j * T] != 0) { if (off < S) wsi[base + off] = v0 + j; off++; }
    }
    if (c == 15)
        for (int j = (total < S ? total : S); j < S; j++) wsi[base + j] = 0;
}

// ---- per-wave 32x32 MFMA tile: A[m][k] row-major, Bt[n][k] row-major ----
template<int K, int LDA, int LDB>
__device__ __forceinline__ void wave_mma(const short* __restrict__ A0,
                                         const short* __restrict__ B0,
                                         f32x4 acc[2][2]) {
    int lane = threadIdx.x & 63;
    int rw = lane & 15, q = lane >> 4;
    const short* ap0 = A0 + rw * LDA + q * 8;
    const short* ap1 = ap0 + 16 * LDA;
    const short* bp0 = B0 + rw * LDB + q * 8;
    const short* bp1 = bp0 + 16 * LDB;
#pragma unroll 4
    for (int kc = 0; kc < K; kc += 32) {
        bf16x8 a0 = *(const bf16x8*)(ap0 + kc);
        bf16x8 a1 = *(const bf16x8*)(ap1 + kc);
        bf16x8 b0 = *(const bf16x8*)(bp0 + kc);
        bf16x8 b1 = *(const bf16x8*)(bp1 + kc);
        acc[0][0] = __builtin_amdgcn_mfma_f32_16x16x32_bf16(a0, b0, acc[0][0], 0, 0, 0);
        acc[0][1] = __builtin_amdgcn_mfma_f32_16x16x32_bf16(a0, b1, acc[0][1], 0, 0, 0);
        acc[1][0] = __builtin_amdgcn_mfma_f32_16x16x32_bf16(a1, b0, acc[1][0], 0, 0, 0);
        acc[1][1] = __builtin_amdgcn_mfma_f32_16x16x32_bf16(a1, b1, acc[1][1], 0, 0, 0);
    }
}

// ---- Wkp = Wu@Wk (bf16 [cv][d]) and WvpT = (Wu@Wv)^T (bf16 [d][cv]); 512 blocks x 1 wave ----
__global__ void g_prep_mfma(float* __restrict__ ws) {
    int w = blockIdx.x;
    int which = w >> 8, rem = w & 255;
    int m0 = (rem >> 5) * 32, n0 = (rem & 31) * 32;  // m: cv(256), n: d(1024)
    const short* A = (const short*)(ws + WUB_O) + (size_t)m0 * DIM;
    const short* Bt = (const short*)(ws + (which ? WVT_O : WKT_O)) + (size_t)n0 * DIM;
    f32x4 acc[2][2] = {};
    wave_mma<DIM, DIM, DIM>(A, Bt, acc);
    int lane = threadIdx.x & 63, col = lane & 15, q = lane >> 4;
    if (which == 0) {
        short* out = (short*)(ws + WKPB_O);
#pragma unroll
        for (int i = 0; i < 2; i++)
#pragma unroll
            for (int j = 0; j < 2; j++)
#pragma unroll
                for (int r = 0; r < 4; r++)
                    out[(size_t)(m0 + i * 16 + q * 4 + r) * DIM + n0 + j * 16 + col] =
                        f2bf(acc[i][j][r]);
    } else {
        short* out = (short*)(ws + WVPT_O);
#pragma unroll
        for (int i = 0; i < 2; i++)
#pragma unroll
            for (int j = 0; j < 2; j++) {
                s16x4 v;
                v.x = f2bf(acc[i][j][0]); v.y = f2bf(acc[i][j][1]);
                v.z = f2bf(acc[i][j][2]); v.w = f2bf(acc[i][j][3]);
                *(s16x4*)&out[(size_t)(n0 + j * 16 + col) * CV + m0 + i * 16 + q * 4] = v;
            }
    }
}

// ---- Z bf16 [bt][cv] = Xb @ Wkp^T; 256 blocks x 1 wave ----
__global__ void g_z_mfma(float* __restrict__ ws) {
    int w = blockIdx.x;
    int m0 = (w >> 3) * 32, n0 = (w & 7) * 32;     // m: bt(1024), n: cv(256)
    const short* A = (const short*)(ws + XB_O) + (size_t)m0 * DIM;
    const short* Bt = (const short*)(ws + WKPB_O) + (size_t)n0 * DIM;
    f32x4 acc[2][2] = {};
    wave_mma<DIM, DIM, DIM>(A, Bt, acc);
    int lane = threadIdx.x & 63, col = lane & 15, q = lane >> 4;
    short* zb = (short*)(ws + ZB_O);
#pragma unroll
    for (int i = 0; i < 2; i++)
#pragma unroll
        for (int j = 0; j < 2; j++)
#pragma unroll
            for (int r = 0; r < 4; r++)
                zb[(size_t)(m0 + i * 16 + q * 4 + r) * CV + n0 + j * 16 + col] =
                    f2bf(acc[i][j][r]);
}

// ---- per (b,t): c0 = x.bk; scores via gathered MFMA; exp; W = sum p*vis_row ----
// 1024 blocks x 64 threads (1 wave)
__global__ void g_attn(const float* __restrict__ x, const float* __restrict__ vision,
                       float* __restrict__ ws, int* __restrict__ wsi) {
    __shared__ float ps[S];
    __shared__ int idxs[S];
    int bt = blockIdx.x, b = bt >> 8;
    int lane = threadIdx.x;
    idxs[lane] = wsi[PIDX_O + bt * S + lane];    // S == 64
    // c0 = x[bt] . bk  (wave butterfly reduce)
    float c0p = 0.f;
    const float4* xr = (const float4*)(x + (size_t)bt * DIM);
    const float4* bkr = (const float4*)(ws + BK_O);
#pragma unroll
    for (int j = 0; j < 4; j++) {
        float4 a = xr[lane + 64 * j], k4 = bkr[lane + 64 * j];
        c0p += a.x * k4.x + a.y * k4.y + a.z * k4.z + a.w * k4.w;
    }
    for (int off = 32; off > 0; off >>= 1) c0p += __shfl_xor(c0p, off);
    float c0 = c0p;
    __syncthreads();
    // scores: A = 16 gathered bf16 vision rows, B = z broadcast into all 16 cols
    int rw = lane & 15, q = lane >> 4;
    const short* vb = (const short*)(ws + VB_O) + (size_t)b * V * CV;
    const short* zp = (const short*)(ws + ZB_O) + (size_t)bt * CV + q * 8;
    f32x4 acc[4] = {};
#pragma unroll
    for (int mt = 0; mt < 4; mt++) {
        const short* ap = vb + (size_t)idxs[mt * 16 + rw] * CV + q * 8;
        f32x4 a4 = {0.f, 0.f, 0.f, 0.f};
#pragma unroll
        for (int kc = 0; kc < CV; kc += 32) {
            bf16x8 av = *(const bf16x8*)(ap + kc);
            bf16x8 bv = *(const bf16x8*)(zp + kc);
            a4 = __builtin_amdgcn_mfma_f32_16x16x32_bf16(av, bv, a4, 0, 0, 0);
        }
        acc[mt] = a4;
    }
    if (rw == 0) {   // C: row m = q*4+r, col = lane&15 (all cols identical)
#pragma unroll
        for (int mt = 0; mt < 4; mt++)
#pragma unroll
            for (int r = 0; r < 4; r++)
                ps[mt * 16 + q * 4 + r] = acc[mt][r];
    }
    __syncthreads();
    float p = expf((ps[lane] + c0) * 0.03125f);
    float rs = p;
    for (int off = 32; off > 0; off >>= 1) rs += __shfl_xor(rs, off);
    ps[lane] = p;
    if (lane == 0) {
        ws[RS_O + bt] = rs;
        atomicAdd(ws + DENOM_O + b, rs);
    }
    __syncthreads();
    // W accum: lane covers cv = lane*4..+3, coalesced f32 vision rows
    float4 wa = {0.f, 0.f, 0.f, 0.f};
    const float* visb = vision + (size_t)b * V * CV;
#pragma unroll 8
    for (int s = 0; s < S; s++) {
        float pv = ps[s];
        float4 vr = *(const float4*)(visb + (size_t)idxs[s] * CV + lane * 4);
        wa.x += pv * vr.x; wa.y += pv * vr.y; wa.z += pv * vr.z; wa.w += pv * vr.w;
    }
    s16x4 o;
    o.x = f2bf(wa.x); o.y = f2bf(wa.y); o.z = f2bf(wa.z); o.w = f2bf(wa.w);
    ((s16x4*)((short*)(ws + WB_O) + (size_t)bt * CV))[lane] = o;
}

// ---- out[bt][d] = x + (Wb @ WvpT^T + rs*bv) / denom; 1024 blocks x 1 wave ----
__global__ void g_out_mfma(const float* __restrict__ x, float* __restrict__ ws,
                           float* __restrict__ out) {
    int w = blockIdx.x;
    int m0 = (w >> 5) * 32, n0 = (w & 31) * 32;    // m: bt(1024), n: d(1024)
    const short* A = (const short*)(ws + WB_O) + (size_t)m0 * CV;
    const short* Bt = (const short*)(ws + WVPT_O) + (size_t)n0 * CV;
    f32x4 acc[2][2] = {};
    wave_mma<CV, CV, CV>(A, Bt, acc);
    int lane = threadIdx.x & 63, col = lane & 15, q = lane >> 4;
#pragma unroll
    for (int i = 0; i < 2; i++)
#pragma unroll
        for (int r = 0; r < 4; r++) {
            int row = m0 + i * 16 + q * 4 + r;
            float rs = ws[RS_O + row];
            float inv = 1.0f / ws[DENOM_O + (row >> 8)];
#pragma unroll
            for (int j = 0; j < 2; j++) {
                int cc = n0 + j * 16 + col;
                out[(size_t)row * DIM + cc] =
                    x[(size_t)row * DIM + cc] + (acc[i][j][r] + rs * ws[BV_O + cc]) * inv;
            }
        }
}

extern "C" void kernel_launch(void* const* d_in, const int* in_sizes, int n_in,
                              void* d_out, int out_size, void* d_ws, size_t ws_size,
                              hipStream_t stream) {
    (void)in_sizes; (void)n_in; (void)out_size; (void)ws_size;
    const float* x      = (const float*)d_in[0];
    const float* vision = (const float*)d_in[1];
    const void*  mask   = d_in[2];
    const float* Wu     = (const float*)d_in[3];
    const float* bu     = (const float*)d_in[4];
    const float* Wk     = (const float*)d_in[5];
    const float* Wv     = (const float*)d_in[6];
    float* out = (float*)d_out;
    float* ws  = (float*)d_ws;
    int*   wsi = (int*)d_ws;

    // zero bk/bv/denom (atomic targets)
    hipMemsetAsync((char*)d_ws + (size_t)BK_O * 4, 0,
                   (size_t)(WS_TOTAL - BK_O) * 4, stream);

    stage1<<<2880, 256, 0, stream>>>(vision, Wu, x, Wk, Wv, bu, mask, ws, wsi);
    g_prep_mfma<<<512, 64, 0, stream>>>(ws);
    g_z_mfma<<<256, 64, 0, stream>>>(ws);
    g_attn<<<1024, 64, 0, stream>>>(x, vision, ws, wsi);
    g_out_mfma<<<1024, 64, 0, stream>>>(x, ws, out);
}